// Round 11
// baseline (993.069 us; speedup 1.0000x reference)
//
#include <hip/hip_runtime.h>

typedef float f32x4 __attribute__((ext_vector_type(4)));
typedef _Float16 f16x8 __attribute__((ext_vector_type(8)));

#define B_TOT   1024
#define D_DIM   128
#define H_DIM   512
#define N_STEPS 500
#define ROWS    4      // batch rows per block
#define WAVES   8      // waves per block

#define HSTRIDE 272                 // bytes per hist row (128 f16 + pad)
#define HSLOT   (8 * HSTRIDE)       // 8 rows (4 hi + 4 lo) per slot
#define BSTRIDE 1056                // bytes per bounce row (512 f16 + pad)
#define LDS_BOUNCE (11 * HSLOT)     // hist occupies [0, 11*HSLOT)
#define LDS_TOTAL  (LDS_BOUNCE + 8 * BSTRIDE)

static __device__ __forceinline__ short f16b(float f) {
    _Float16 h = (_Float16)f;
    return __builtin_bit_cast(short, h);
}
static __device__ __forceinline__ float f16tof(short s) {
    return (float)__builtin_bit_cast(_Float16, s);
}
static __device__ __forceinline__ float tanh_fast(float x) {
    float e = __builtin_amdgcn_exp2f(x * 2.885390081777927f);
    return 1.0f - 2.0f * __builtin_amdgcn_rcpf(e + 1.0f);
}
static __device__ __forceinline__ f32x4 sx32(f32x4 v) {
    f32x4 r;
#pragma unroll
    for (int i = 0; i < 4; ++i) r[i] = __shfl_xor(v[i], 32);
    return r;
}
// dynamic element pick via cndmask tree (no scratch)
static __device__ __forceinline__ float pick(f32x4 v, int g) {
    float lo = (g & 1) ? v[1] : v[0];
    float hi = (g & 1) ? v[3] : v[2];
    return (g & 2) ? hi : lo;
}
// LDS-only barrier (global stores may stay in flight)
static __device__ __forceinline__ void barrier_lds() {
    asm volatile("s_waitcnt lgkmcnt(0)" ::: "memory");
    __builtin_amdgcn_s_barrier();
}

__global__ __launch_bounds__(512, 2) void ndde_kernel(
    const float* __restrict__ x0, const float* __restrict__ tau,
    const float* __restrict__ W1, const float* __restrict__ b1,
    const float* __restrict__ W2, const float* __restrict__ b2,
    float* __restrict__ out)
{
    __shared__ __align__(16) char smem[LDS_TOTAL];

    const int tid = threadIdx.x;
    const int w   = tid >> 6;
    const int l   = tid & 63;
    const int g   = l >> 4;
    const int l15 = l & 15;
    // A-frag row = l15; rows [0-3]=hi b0-3, [4-7]=dup, [8-11]=lo b0-3, [12-15]=dup
    const int ur  = (l15 & 3) | ((l15 >> 3) << 2);   // storage row 0..7
    const int r0  = blockIdx.x * ROWS;
    const int d   = 16 * w + l15;                    // this lane's owned d-col

    const float dtv = tau[0] * 0.1f;

    // ---------------- weights -> registers (fp16, compiler-managed) ----------------
    f16x8 w1f[4][8];   // [nt over 64 h-rows][ks over K=256]  (x: ks0-3, y: ks4-7)
    f16x8 w2f[16];     // [ks over K=512], B-frag cols = d in [16w, 16w+16)
    float b1f[4], w1tf[4];

#pragma unroll
    for (int nt = 0; nt < 4; ++nt) {
        const int hr = 64 * w + 16 * nt + l15;
        const float* wr = W1 + (long)hr * 257;
#pragma unroll
        for (int ks = 0; ks < 8; ++ks) {
            const int c0 = 32 * ks + 8 * g;
            f16x8 f;
#pragma unroll
            for (int j = 0; j < 8; ++j) f[j] = (_Float16)wr[c0 + j];
            w1f[nt][ks] = f;
        }
        b1f[nt]  = b1[hr];
        w1tf[nt] = wr[256];
    }
    {
        const float* wr = W2 + (long)d * 512;
#pragma unroll
        for (int ks = 0; ks < 16; ++ks) {
            const int c0 = 32 * ks + 8 * g;
            f16x8 f;
#pragma unroll
            for (int j = 0; j < 8; ++j) f[j] = (_Float16)wr[c0 + j];
            w2f[ks] = f;
        }
    }
    const float b2v = b2[d];
    float xo = x0[(long)(r0 + g) * D_DIM + d];   // lane-owned state (r=g, d)

    // ---------------- init hist ring + out[0] ----------------
    {
        short hb = f16b(xo);
        short lb = f16b(xo - f16tof(hb));
        for (int s = 0; s < 11; ++s) {
            *(short*)(smem + s * HSLOT + g * HSTRIDE + 2 * d)       = hb;
            *(short*)(smem + s * HSLOT + (g + 4) * HSTRIDE + 2 * d) = lb;
        }
        out[(long)(r0 + g) * D_DIM + d] = xo;
    }
    __syncthreads();

    // per-lane invariant LDS offsets
    const int histRd   = ur * HSTRIDE + 16 * g;                              // + slot*HSLOT + 64*ks
    const int bounceRd = LDS_BOUNCE + ur * BSTRIDE + ((16 * g) ^ ((ur & 3) << 4)); // + 64*ks
    const int bwXor    = g << 4;   // write-side XOR (row g)

    float* po = out + (long)(B_TOT * D_DIM) + (long)(r0 + g) * D_DIM + d;

    int cur = 0;   // hist slot holding x_n
    int ys  = 1;   // slot holding y_n = x_{n-10}; overwritten with x_{n+1}

    // ---- prologue: y-part of GEMM1 for step 0 (slot 1 = x0 history) ----
    f32x4 accY[4];
#pragma unroll
    for (int nt = 0; nt < 4; ++nt) accY[nt] = (f32x4){0.f, 0.f, 0.f, 0.f};
    {
        const char* yb = smem + 1 * HSLOT + histRd;
#pragma unroll
        for (int ks = 0; ks < 4; ++ks) {
            f16x8 ya = *(const f16x8*)(yb + 64 * ks);
#pragma unroll
            for (int nt = 0; nt < 4; ++nt)
                accY[nt] = __builtin_amdgcn_mfma_f32_16x16x32_f16(ya, w1f[nt][ks + 4], accY[nt], 0, 0, 0);
        }
    }

#pragma clang loop unroll(disable)
    for (int n = 0; n < N_STEPS; ++n) {
        const float t = (float)n * dtv;

        // -------- GEMM1 x-part (critical path): accY already holds y-part --------
        const char* xb = smem + cur * HSLOT + histRd;
#pragma unroll
        for (int ks = 0; ks < 4; ++ks) {
            f16x8 xa = *(const f16x8*)(xb + 64 * ks);
#pragma unroll
            for (int nt = 0; nt < 4; ++nt)
                accY[nt] = __builtin_amdgcn_mfma_f32_16x16x32_f16(xa, w1f[nt][ks], accY[nt], 0, 0, 0);
        }

        // combine hi+lo rows (lane^32), bias, tanh, write bounce
#pragma unroll
        for (int nt = 0; nt < 4; ++nt) {
            f32x4 c = accY[nt];
            c += sx32(c);
            float hp = pick(c, g) + fmaf(t, w1tf[nt], b1f[nt]);
            float h  = tanh_fast(hp);
            short hh = f16b(h);
            short hl = f16b(h - f16tof(hh));
            const int cb = (2 * (64 * w + 16 * nt + l15)) ^ bwXor;
            *(short*)(smem + LDS_BOUNCE + g * BSTRIDE + cb)       = hh;
            *(short*)(smem + LDS_BOUNCE + (g + 4) * BSTRIDE + cb) = hl;
        }
        barrier_lds();

        // -------- GEMM2: full K=512, 4 independent chains --------
        f32x4 a2c[4];
#pragma unroll
        for (int c = 0; c < 4; ++c) {
            a2c[c] = (f32x4){0.f, 0.f, 0.f, 0.f};
#pragma unroll
            for (int k = 0; k < 4; ++k) {
                f16x8 ha = *(const f16x8*)(smem + bounceRd + 64 * (4 * c + k));
                a2c[c] = __builtin_amdgcn_mfma_f32_16x16x32_f16(ha, w2f[4 * c + k], a2c[c], 0, 0, 0);
            }
        }

        // -------- y-part precompute for step n+1 (hides in GEMM2 shadow) --------
        const int ysN = (ys == 10) ? 0 : ys + 1;   // slot of y_{n+1} = x_{n-9}
#pragma unroll
        for (int nt = 0; nt < 4; ++nt) accY[nt] = (f32x4){0.f, 0.f, 0.f, 0.f};
        {
            const char* yb = smem + ysN * HSLOT + histRd;
#pragma unroll
            for (int ks = 0; ks < 4; ++ks) {
                f16x8 ya = *(const f16x8*)(yb + 64 * ks);
#pragma unroll
                for (int nt = 0; nt < 4; ++nt)
                    accY[nt] = __builtin_amdgcn_mfma_f32_16x16x32_f16(ya, w1f[nt][ks + 4], accY[nt], 0, 0, 0);
            }
        }

        // -------- fold chains + Euler update + emit --------
        f32x4 acc2 = (a2c[0] + a2c[1]) + (a2c[2] + a2c[3]);
        acc2 += sx32(acc2);
        const float o  = pick(acc2, g) + b2v;
        const float xn = fmaf(dtv, o, xo);
        xo = xn;
        {
            short hb = f16b(xn);
            short lb = f16b(xn - f16tof(hb));
            *(short*)(smem + ys * HSLOT + g * HSTRIDE + 2 * d)       = hb;   // x_{n+1} -> slot ys
            *(short*)(smem + ys * HSLOT + (g + 4) * HSTRIDE + 2 * d) = lb;
        }
        *po = xn;
        po += B_TOT * D_DIM;

        cur = ys;
        ys  = ysN;
        barrier_lds();
    }
}

extern "C" void kernel_launch(void* const* d_in, const int* in_sizes, int n_in,
                              void* d_out, int out_size, void* d_ws, size_t ws_size,
                              hipStream_t stream) {
    (void)in_sizes; (void)n_in; (void)out_size; (void)d_ws; (void)ws_size;
    const float* x0  = (const float*)d_in[0];
    const float* tau = (const float*)d_in[1];
    const float* W1  = (const float*)d_in[2];
    const float* b1  = (const float*)d_in[3];
    const float* W2  = (const float*)d_in[4];
    const float* b2  = (const float*)d_in[5];
    float* out = (float*)d_out;

    ndde_kernel<<<dim3(B_TOT / ROWS), dim3(64 * WAVES), 0, stream>>>(
        x0, tau, W1, b1, W2, b2, out);
}

// Round 12
// 939.495 us; speedup vs baseline: 1.0570x; 1.0570x over previous
//
#include <hip/hip_runtime.h>

typedef float f32x4 __attribute__((ext_vector_type(4)));
typedef _Float16 f16x8 __attribute__((ext_vector_type(8)));

#define B_TOT   1024
#define D_DIM   128
#define H_DIM   512
#define N_STEPS 500
#define ROWS    4      // batch rows per block
#define WAVES   8      // waves per block

#define HSTRIDE 272                 // bytes per hist row (128 f16 + pad)
#define HSLOT   (8 * HSTRIDE)       // 8 rows (4 hi + 4 lo) per slot
#define BSTRIDE 1056                // bytes per bounce row (512 f16 + pad)
#define LDS_BOUNCE (11 * HSLOT)     // hist occupies [0, 11*HSLOT)
#define LDS_TOTAL  (LDS_BOUNCE + 8 * BSTRIDE)

static __device__ __forceinline__ short f16b(float f) {
    _Float16 h = (_Float16)f;
    return __builtin_bit_cast(short, h);
}
static __device__ __forceinline__ float f16tof(short s) {
    return (float)__builtin_bit_cast(_Float16, s);
}
static __device__ __forceinline__ float tanh_fast(float x) {
    float e = __builtin_amdgcn_exp2f(x * 2.885390081777927f);
    return 1.0f - 2.0f * __builtin_amdgcn_rcpf(e + 1.0f);
}
static __device__ __forceinline__ f32x4 sx32(f32x4 v) {
    f32x4 r;
#pragma unroll
    for (int i = 0; i < 4; ++i) r[i] = __shfl_xor(v[i], 32);
    return r;
}
// dynamic element pick via cndmask tree (no scratch)
static __device__ __forceinline__ float pick(f32x4 v, int g) {
    float lo = (g & 1) ? v[1] : v[0];
    float hi = (g & 1) ? v[3] : v[2];
    return (g & 2) ? hi : lo;
}
// LDS-only barrier (global stores may stay in flight)
static __device__ __forceinline__ void barrier_lds() {
    asm volatile("s_waitcnt lgkmcnt(0)" ::: "memory");
    __builtin_amdgcn_s_barrier();
}

__global__ __launch_bounds__(512)
__attribute__((amdgpu_waves_per_eu(2, 2)))
void ndde_kernel(
    const float* __restrict__ x0, const float* __restrict__ tau,
    const float* __restrict__ W1, const float* __restrict__ b1,
    const float* __restrict__ W2, const float* __restrict__ b2,
    float* __restrict__ out)
{
    __shared__ __align__(16) char smem[LDS_TOTAL];

    const int tid = threadIdx.x;
    const int w   = tid >> 6;
    const int l   = tid & 63;
    const int g   = l >> 4;
    const int l15 = l & 15;
    // A-frag row = l15; rows [0-3]=hi b0-3, [4-7]=dup, [8-11]=lo b0-3, [12-15]=dup
    const int ur  = (l15 & 3) | ((l15 >> 3) << 2);   // storage row 0..7
    const int r0  = blockIdx.x * ROWS;
    const int d   = 16 * w + l15;                    // this lane's owned d-col

    const float dtv = tau[0] * 0.1f;

    // ---------------- weights -> registers (fp16, compiler-managed) ----------------
    f16x8 w1f[4][8];   // [nt over 64 h-rows][ks over K=256]  (x: ks0-3, y: ks4-7)
    f16x8 w2f[16];     // [ks over K=512], B-frag cols = d in [16w, 16w+16)
    float b1f[4], w1tf[4];

#pragma unroll
    for (int nt = 0; nt < 4; ++nt) {
        const int hr = 64 * w + 16 * nt + l15;
        const float* wr = W1 + (long)hr * 257;
#pragma unroll
        for (int ks = 0; ks < 8; ++ks) {
            const int c0 = 32 * ks + 8 * g;
            f16x8 f;
#pragma unroll
            for (int j = 0; j < 8; ++j) f[j] = (_Float16)wr[c0 + j];
            w1f[nt][ks] = f;
        }
        b1f[nt]  = b1[hr];
        w1tf[nt] = wr[256];
    }
    {
        const float* wr = W2 + (long)d * 512;
#pragma unroll
        for (int ks = 0; ks < 16; ++ks) {
            const int c0 = 32 * ks + 8 * g;
            f16x8 f;
#pragma unroll
            for (int j = 0; j < 8; ++j) f[j] = (_Float16)wr[c0 + j];
            w2f[ks] = f;
        }
    }
    const float b2v = b2[d];
    float xo = x0[(long)(r0 + g) * D_DIM + d];   // lane-owned state (r=g, d)

    // ---------------- init hist ring + out[0] ----------------
    {
        short hb = f16b(xo);
        short lb = f16b(xo - f16tof(hb));
        for (int s = 0; s < 11; ++s) {
            *(short*)(smem + s * HSLOT + g * HSTRIDE + 2 * d)       = hb;
            *(short*)(smem + s * HSLOT + (g + 4) * HSTRIDE + 2 * d) = lb;
        }
        out[(long)(r0 + g) * D_DIM + d] = xo;
    }
    __syncthreads();

    // per-lane invariant LDS offsets
    const int histRd   = ur * HSTRIDE + 16 * g;                              // + slot*HSLOT + 64*ks
    const int bounceRd = LDS_BOUNCE + ur * BSTRIDE + ((16 * g) ^ ((ur & 3) << 4)); // + 64*ks
    const int bwXor    = g << 4;   // write-side XOR (row g)

    float* po = out + (long)(B_TOT * D_DIM) + (long)(r0 + g) * D_DIM + d;

    int cur = 0;   // hist slot holding x_n
    int ys  = 1;   // slot holding y_n = x_{n-10}; overwritten with x_{n+1}

    // ---- prologue: y-part of GEMM1 for step 0 (slot 1 = x0 history) ----
    f32x4 accY[4];
#pragma unroll
    for (int nt = 0; nt < 4; ++nt) accY[nt] = (f32x4){0.f, 0.f, 0.f, 0.f};
    {
        const char* yb = smem + 1 * HSLOT + histRd;
#pragma unroll
        for (int ks = 0; ks < 4; ++ks) {
            f16x8 ya = *(const f16x8*)(yb + 64 * ks);
#pragma unroll
            for (int nt = 0; nt < 4; ++nt)
                accY[nt] = __builtin_amdgcn_mfma_f32_16x16x32_f16(ya, w1f[nt][ks + 4], accY[nt], 0, 0, 0);
        }
    }

#pragma clang loop unroll(disable)
    for (int n = 0; n < N_STEPS; ++n) {
        const float t = (float)n * dtv;

        // -------- GEMM1 x-part (critical path): accY already holds y-part --------
        const char* xb = smem + cur * HSLOT + histRd;
#pragma unroll
        for (int ks = 0; ks < 4; ++ks) {
            f16x8 xa = *(const f16x8*)(xb + 64 * ks);
#pragma unroll
            for (int nt = 0; nt < 4; ++nt)
                accY[nt] = __builtin_amdgcn_mfma_f32_16x16x32_f16(xa, w1f[nt][ks], accY[nt], 0, 0, 0);
        }

        // combine hi+lo rows (lane^32), bias, tanh, write bounce
#pragma unroll
        for (int nt = 0; nt < 4; ++nt) {
            f32x4 c = accY[nt];
            c += sx32(c);
            float hp = pick(c, g) + fmaf(t, w1tf[nt], b1f[nt]);
            float h  = tanh_fast(hp);
            short hh = f16b(h);
            short hl = f16b(h - f16tof(hh));
            const int cb = (2 * (64 * w + 16 * nt + l15)) ^ bwXor;
            *(short*)(smem + LDS_BOUNCE + g * BSTRIDE + cb)       = hh;
            *(short*)(smem + LDS_BOUNCE + (g + 4) * BSTRIDE + cb) = hl;
        }
        barrier_lds();

        // -------- GEMM2: full K=512, 4 independent chains --------
        f32x4 a2c[4];
#pragma unroll
        for (int c = 0; c < 4; ++c) {
            a2c[c] = (f32x4){0.f, 0.f, 0.f, 0.f};
#pragma unroll
            for (int k = 0; k < 4; ++k) {
                f16x8 ha = *(const f16x8*)(smem + bounceRd + 64 * (4 * c + k));
                a2c[c] = __builtin_amdgcn_mfma_f32_16x16x32_f16(ha, w2f[4 * c + k], a2c[c], 0, 0, 0);
            }
        }

        // -------- y-part precompute for step n+1 (hides in GEMM2 shadow) --------
        const int ysN = (ys == 10) ? 0 : ys + 1;   // slot of y_{n+1} = x_{n-9}
#pragma unroll
        for (int nt = 0; nt < 4; ++nt) accY[nt] = (f32x4){0.f, 0.f, 0.f, 0.f};
        {
            const char* yb = smem + ysN * HSLOT + histRd;
#pragma unroll
            for (int ks = 0; ks < 4; ++ks) {
                f16x8 ya = *(const f16x8*)(yb + 64 * ks);
#pragma unroll
                for (int nt = 0; nt < 4; ++nt)
                    accY[nt] = __builtin_amdgcn_mfma_f32_16x16x32_f16(ya, w1f[nt][ks + 4], accY[nt], 0, 0, 0);
            }
        }

        // -------- fold chains + Euler update + emit --------
        f32x4 acc2 = (a2c[0] + a2c[1]) + (a2c[2] + a2c[3]);
        acc2 += sx32(acc2);
        const float o  = pick(acc2, g) + b2v;
        const float xn = fmaf(dtv, o, xo);
        xo = xn;
        {
            short hb = f16b(xn);
            short lb = f16b(xn - f16tof(hb));
            *(short*)(smem + ys * HSLOT + g * HSTRIDE + 2 * d)       = hb;   // x_{n+1} -> slot ys
            *(short*)(smem + ys * HSLOT + (g + 4) * HSTRIDE + 2 * d) = lb;
        }
        __builtin_nontemporal_store(xn, po);   // write-only trajectory stream
        po += B_TOT * D_DIM;

        cur = ys;
        ys  = ysN;
        barrier_lds();
    }
}

extern "C" void kernel_launch(void* const* d_in, const int* in_sizes, int n_in,
                              void* d_out, int out_size, void* d_ws, size_t ws_size,
                              hipStream_t stream) {
    (void)in_sizes; (void)n_in; (void)out_size; (void)d_ws; (void)ws_size;
    const float* x0  = (const float*)d_in[0];
    const float* tau = (const float*)d_in[1];
    const float* W1  = (const float*)d_in[2];
    const float* b1  = (const float*)d_in[3];
    const float* W2  = (const float*)d_in[4];
    const float* b2  = (const float*)d_in[5];
    float* out = (float*)d_out;

    ndde_kernel<<<dim3(B_TOT / ROWS), dim3(64 * WAVES), 0, stream>>>(
        x0, tau, W1, b1, W2, b2, out);
}

// Round 13
// 895.109 us; speedup vs baseline: 1.1094x; 1.0496x over previous
//
#include <hip/hip_runtime.h>

typedef float f32x4 __attribute__((ext_vector_type(4)));
typedef _Float16 f16x8 __attribute__((ext_vector_type(8)));

#define B_TOT   1024
#define D_DIM   128
#define N_STEPS 500
#define ROWS    4      // batch rows per block
#define WAVES   8      // waves per block

#define HSTRIDE 272                 // bytes per hist row (128 f16 + pad)
#define HSLOT   (8 * HSTRIDE)       // 8 rows: {b0h,b0l,b1h,b1l,b2h,b2l,b3h,b3l}
#define BSTRIDE 1056                // bytes per bounce row (512 f16 + pad)
#define LDS_BOUNCE (11 * HSLOT)
#define LDS_TOTAL  (LDS_BOUNCE + 8 * BSTRIDE)

static __device__ __forceinline__ short f16b(float f) {
    _Float16 h = (_Float16)f;
    return __builtin_bit_cast(short, h);
}
static __device__ __forceinline__ float f16tof(short s) {
    return (float)__builtin_bit_cast(_Float16, s);
}
static __device__ __forceinline__ float tanh_fast(float x) {
    float e = __builtin_amdgcn_exp2f(x * 2.885390081777927f);
    return 1.0f - 2.0f * __builtin_amdgcn_rcpf(e + 1.0f);
}
// LDS-only barrier (global stores may stay in flight)
static __device__ __forceinline__ void barrier_lds() {
    asm volatile("s_waitcnt lgkmcnt(0)" ::: "memory");
    __builtin_amdgcn_s_barrier();
}

__global__ __launch_bounds__(512)
__attribute__((amdgpu_waves_per_eu(2, 2)))
void ndde_kernel(
    const float* __restrict__ x0, const float* __restrict__ tau,
    const float* __restrict__ W1, const float* __restrict__ b1,
    const float* __restrict__ W2, const float* __restrict__ b2,
    float* __restrict__ out)
{
    __shared__ __align__(16) char smem[LDS_TOTAL];

    const int tid = threadIdx.x;
    const int w   = tid >> 6;
    const int l   = tid & 63;
    const int g   = l >> 4;
    const int l15 = l & 15;
    const int hs  = (l >> 4) & 1;       // batch-pair selector: 0 -> b{0,1}, 1 -> b{2,3}
    const int bb  = 2 * hs;             // first batch of this lane's pair
    const bool act = (l < 32);          // lanes 32-63 are M-row duplicates
    const int r0  = blockIdx.x * ROWS;
    const int d   = 16 * w + l15;       // this lane's owned d-col (GEMM2 N)
    const int rb  = tid >> 7;           // init identity: batch
    const int rd  = tid & 127;          // and d-column

    const float dtv = tau[0] * 0.1f;

    // ---------------- weights -> registers (fp16, compiler-managed) ----------------
    f16x8 w1f[4][8];   // [nt over 64 h-rows][ks over K=256]  (x: ks0-3, y: ks4-7)
    f16x8 w2f[16];     // [ks over K=512], B-frag cols = d in [16w, 16w+16)
    float b1f[4], w1tf[4];

#pragma unroll
    for (int nt = 0; nt < 4; ++nt) {
        const int hr = 64 * w + 16 * nt + l15;
        const float* wr = W1 + (long)hr * 257;
#pragma unroll
        for (int ks = 0; ks < 8; ++ks) {
            const int c0 = 32 * ks + 8 * g;
            f16x8 f;
#pragma unroll
            for (int j = 0; j < 8; ++j) f[j] = (_Float16)wr[c0 + j];
            w1f[nt][ks] = f;
        }
        b1f[nt]  = b1[hr];
        w1tf[nt] = wr[256];
    }
    {
        const float* wr = W2 + (long)d * 512;
#pragma unroll
        for (int ks = 0; ks < 16; ++ks) {
            const int c0 = 32 * ks + 8 * g;
            f16x8 f;
#pragma unroll
            for (int j = 0; j < 8; ++j) f[j] = (_Float16)wr[c0 + j];
            w2f[ks] = f;
        }
    }
    const float b2v = b2[d];
    // lane-owned state: batches bb, bb+1 at column d (dup in upper half)
    float xo0 = x0[(long)(r0 + bb)     * D_DIM + d];
    float xo1 = x0[(long)(r0 + bb + 1) * D_DIM + d];

    // ---------------- init hist ring (rows 2b+part) + out[0] ----------------
    {
        float v = x0[(long)(r0 + rb) * D_DIM + rd];
        short hb = f16b(v);
        short lb = f16b(v - f16tof(hb));
        for (int s = 0; s < 11; ++s) {
            char* sl = smem + s * HSLOT;
            *(short*)(sl + (2 * rb)     * HSTRIDE + 2 * rd) = hb;
            *(short*)(sl + (2 * rb + 1) * HSTRIDE + 2 * rd) = lb;
        }
        out[(long)(r0 + rb) * D_DIM + rd] = v;
    }
    __syncthreads();

    // per-lane invariant LDS offsets
    const int hrw     = l15 & 7;                                   // A-frag row (dup 8-15)
    const int histRd  = hrw * HSTRIDE + 16 * g;                    // + slot*HSLOT + 64*ks
    const int bounceRd = LDS_BOUNCE + hrw * BSTRIDE
                       + ((16 * g) ^ (((hrw >> 2) & 1) << 5));     // + 64*ks
    const int xrw     = hs << 5;                                   // write byte-XOR (rows 4-7)
    const int brow0   = 4 * hs;                                    // writer's first bounce row

    float* po0 = out + (long)(B_TOT * D_DIM) + (long)(r0 + bb) * D_DIM + d;

    int cur = 0;   // hist slot holding x_n
    int ys  = 1;   // slot holding y_n = x_{n-10}; overwritten with x_{n+1}

    // ---- prologue: y-part of GEMM1 for step 0 (slot 1 = x0 history) ----
    f32x4 accY[4];
#pragma unroll
    for (int nt = 0; nt < 4; ++nt) accY[nt] = (f32x4){0.f, 0.f, 0.f, 0.f};
    {
        const char* yb = smem + 1 * HSLOT + histRd;
#pragma unroll
        for (int ks = 0; ks < 4; ++ks) {
            f16x8 ya = *(const f16x8*)(yb + 64 * ks);
#pragma unroll
            for (int nt = 0; nt < 4; ++nt)
                accY[nt] = __builtin_amdgcn_mfma_f32_16x16x32_f16(ya, w1f[nt][ks + 4], accY[nt], 0, 0, 0);
        }
    }

#pragma clang loop unroll(disable)
    for (int n = 0; n < N_STEPS; ++n) {
        const float t = (float)n * dtv;

        // -------- GEMM1 x-part (critical path): accY already holds y-part --------
        const char* xb = smem + cur * HSLOT + histRd;
#pragma unroll
        for (int ks = 0; ks < 4; ++ks) {
            f16x8 xa = *(const f16x8*)(xb + 64 * ks);
#pragma unroll
            for (int nt = 0; nt < 4; ++nt)
                accY[nt] = __builtin_amdgcn_mfma_f32_16x16x32_f16(xa, w1f[nt][ks], accY[nt], 0, 0, 0);
        }

        // -------- lane-local hi+lo combine, bias, tanh, bounce write --------
        // C rows (lane-local regs): {2b_hi, 2b_lo, 2b+1_hi, 2b+1_lo} for this lane's pair
#pragma unroll
        for (int nt = 0; nt < 4; ++nt) {
            float sb = fmaf(t, w1tf[nt], b1f[nt]);
            float h0 = tanh_fast(accY[nt][0] + accY[nt][1] + sb);
            float h1 = tanh_fast(accY[nt][2] + accY[nt][3] + sb);
            short h0h = f16b(h0);
            short h0l = f16b(h0 - f16tof(h0h));
            short h1h = f16b(h1);
            short h1l = f16b(h1 - f16tof(h1h));
            if (act) {
                const int cb = (2 * (64 * w + 16 * nt + l15)) ^ xrw;
                char* base = smem + LDS_BOUNCE;
                *(short*)(base + (brow0 + 0) * BSTRIDE + cb) = h0h;
                *(short*)(base + (brow0 + 1) * BSTRIDE + cb) = h0l;
                *(short*)(base + (brow0 + 2) * BSTRIDE + cb) = h1h;
                *(short*)(base + (brow0 + 3) * BSTRIDE + cb) = h1l;
            }
        }
        barrier_lds();

        // -------- GEMM2: full K=512, 4 independent chains --------
        f32x4 a2c[4];
#pragma unroll
        for (int c = 0; c < 4; ++c) {
            a2c[c] = (f32x4){0.f, 0.f, 0.f, 0.f};
#pragma unroll
            for (int k = 0; k < 4; ++k) {
                f16x8 ha = *(const f16x8*)(smem + bounceRd + 64 * (4 * c + k));
                a2c[c] = __builtin_amdgcn_mfma_f32_16x16x32_f16(ha, w2f[4 * c + k], a2c[c], 0, 0, 0);
            }
        }

        // -------- y-part precompute for step n+1 (hides in GEMM2 shadow) --------
        const int ysN = (ys == 10) ? 0 : ys + 1;   // slot of y_{n+1} = x_{n-9}
#pragma unroll
        for (int nt = 0; nt < 4; ++nt) accY[nt] = (f32x4){0.f, 0.f, 0.f, 0.f};
        {
            const char* yb = smem + ysN * HSLOT + histRd;
#pragma unroll
            for (int ks = 0; ks < 4; ++ks) {
                f16x8 ya = *(const f16x8*)(yb + 64 * ks);
#pragma unroll
                for (int nt = 0; nt < 4; ++nt)
                    accY[nt] = __builtin_amdgcn_mfma_f32_16x16x32_f16(ya, w1f[nt][ks + 4], accY[nt], 0, 0, 0);
            }
        }

        // -------- lane-local fold + Euler update + emit (2 batches/lane) --------
        f32x4 acc2 = (a2c[0] + a2c[1]) + (a2c[2] + a2c[3]);
        const float xn0 = fmaf(dtv, (acc2[0] + acc2[1]) + b2v, xo0);
        const float xn1 = fmaf(dtv, (acc2[2] + acc2[3]) + b2v, xo1);
        xo0 = xn0;
        xo1 = xn1;
        if (act) {
            short h0h = f16b(xn0);
            short h0l = f16b(xn0 - f16tof(h0h));
            short h1h = f16b(xn1);
            short h1l = f16b(xn1 - f16tof(h1h));
            char* sl = smem + ys * HSLOT + 2 * d;
            *(short*)(sl + (2 * bb)     * HSTRIDE) = h0h;   // x_{n+1} -> slot ys
            *(short*)(sl + (2 * bb + 1) * HSTRIDE) = h0l;
            *(short*)(sl + (2 * bb + 2) * HSTRIDE) = h1h;
            *(short*)(sl + (2 * bb + 3) * HSTRIDE) = h1l;
            __builtin_nontemporal_store(xn0, po0);
            __builtin_nontemporal_store(xn1, po0 + D_DIM);
        }
        po0 += B_TOT * D_DIM;

        cur = ys;
        ys  = ysN;
        barrier_lds();
    }
}

extern "C" void kernel_launch(void* const* d_in, const int* in_sizes, int n_in,
                              void* d_out, int out_size, void* d_ws, size_t ws_size,
                              hipStream_t stream) {
    (void)in_sizes; (void)n_in; (void)out_size; (void)d_ws; (void)ws_size;
    const float* x0  = (const float*)d_in[0];
    const float* tau = (const float*)d_in[1];
    const float* W1  = (const float*)d_in[2];
    const float* b1  = (const float*)d_in[3];
    const float* W2  = (const float*)d_in[4];
    const float* b2  = (const float*)d_in[5];
    float* out = (float*)d_out;

    ndde_kernel<<<dim3(B_TOT / ROWS), dim3(64 * WAVES), 0, stream>>>(
        x0, tau, W1, b1, W2, b2, out);
}